// Round 1
// baseline (508.951 us; speedup 1.0000x reference)
//
#include <hip/hip_runtime.h>
#include <hip/hip_bf16.h>

#define B_  2
#define D_  256
#define H_  8
#define T_  128
#define S_  128
#define F_  64
#define C_  512
#define TE_ 512

typedef _Float16 f16x8 __attribute__((ext_vector_type(8)));
typedef _Float16 f16x4 __attribute__((ext_vector_type(4)));
typedef float    f32x4 __attribute__((ext_vector_type(4)));

// ---------------------------------------------------------------------------
// K1: time_proj[b*T+t][c] = temb[b,t,:] @ w_time[:,c] + b_time[c] + b_dist[c]
// 128 blocks x 256 threads, 2 rows per block (shares the w_time stream).
// ---------------------------------------------------------------------------
__global__ __launch_bounds__(256) void k_time_proj(
    const float* __restrict__ temb, const float* __restrict__ w_time,
    const float* __restrict__ b_time, const float* __restrict__ b_dist,
    float* __restrict__ tp)
{
    int row0 = blockIdx.x * 2;
    int tid  = threadIdx.x;
    __shared__ float te[2][TE_];
    for (int i = tid; i < 2 * TE_; i += 256)
        te[i >> 9][i & 511] = temb[(size_t)row0 * TE_ + i];
    __syncthreads();
    for (int half = 0; half < 2; ++half) {
        int c = tid + half * 256;
        float bias = b_time[c] + b_dist[c];
        float a0 = bias, a1 = bias;
        for (int e = 0; e < TE_; ++e) {
            float w = w_time[(size_t)e * C_ + c];
            a0 += te[0][e] * w;
            a1 += te[1][e] * w;
        }
        tp[(size_t)row0 * C_ + c]       = a0;
        tp[(size_t)(row0 + 1) * C_ + c] = a1;
    }
}

// ---------------------------------------------------------------------------
// K2: A[row][c] = f16( silu( tp[bt][c] + f0*wd0[c] + f1*wd1[c] + f2*wd2[c] ) )
// row = (b*T+t)*S + s ; 32768 blocks x 128 threads, 4 channels per thread.
// ---------------------------------------------------------------------------
__global__ __launch_bounds__(128) void k_embed_silu(
    const float* __restrict__ tp, const int* __restrict__ pd,
    const float* __restrict__ w_dist, _Float16* __restrict__ A)
{
    int row = blockIdx.x;
    int bt  = row >> 7;            // row / S_
    int d   = pd[row];
    float f0 = log1pf(fmaxf((float)d, 0.f));
    float f1 = log1pf(fmaxf((float)(-d), 0.f));
    float f2 = (d == 0) ? 1.f : 0.f;
    int c0 = threadIdx.x * 4;
    float4 t4 = *(const float4*)&tp[(size_t)bt * C_ + c0];
    float4 w0 = *(const float4*)&w_dist[c0];
    float4 w1 = *(const float4*)&w_dist[C_ + c0];
    float4 w2 = *(const float4*)&w_dist[2 * C_ + c0];
    float e0 = t4.x + f0 * w0.x + f1 * w1.x + f2 * w2.x;
    float e1 = t4.y + f0 * w0.y + f1 * w1.y + f2 * w2.y;
    float e2 = t4.z + f0 * w0.z + f1 * w1.z + f2 * w2.z;
    float e3 = t4.w + f0 * w0.w + f1 * w1.w + f2 * w2.w;
    f16x4 v;
    v.x = (_Float16)(e0 / (1.f + expf(-e0)));
    v.y = (_Float16)(e1 / (1.f + expf(-e1)));
    v.z = (_Float16)(e2 / (1.f + expf(-e2)));
    v.w = (_Float16)(e3 / (1.f + expf(-e3)));
    *(f16x4*)&A[(size_t)row * C_ + c0] = v;
}

// ---------------------------------------------------------------------------
// K2b: Wt[n][k] = f16(w_out[k][n])   (512 x 512)
// ---------------------------------------------------------------------------
__global__ __launch_bounds__(512) void k_wt(
    const float* __restrict__ w_out, _Float16* __restrict__ Wt)
{
    int n = blockIdx.x;
    int k = threadIdx.x;
    Wt[(size_t)n * C_ + k] = (_Float16)w_out[(size_t)k * C_ + n];
}

// ---------------------------------------------------------------------------
// K3: R = A(32768x512) @ Wt^T(512x512) + b_out   -> f16
// 128x128 tile, BK=64, 256 threads (4 waves, 2x2), mfma_f32_16x16x32_f16.
// ---------------------------------------------------------------------------
__global__ __launch_bounds__(256) void k_gemm_R(
    const _Float16* __restrict__ A, const _Float16* __restrict__ Wt,
    const float* __restrict__ b_out, _Float16* __restrict__ R)
{
    const int K = 512, N = 512;
    __shared__ _Float16 As[128][72];   // +8 pad: 2-way-max bank aliasing
    __shared__ _Float16 Bs[128][72];
    int bm = blockIdx.x, bn = blockIdx.y;
    int tid = threadIdx.x;
    int wave = tid >> 6, lane = tid & 63;
    int wm = (wave >> 1) * 64, wn = (wave & 1) * 64;
    int mrow = lane & 15, kq = (lane >> 4) * 8;
    int lrow = tid >> 3, lcol = (tid & 7) * 8;
    const size_t arow0 = (size_t)bm * 128;
    f32x4 acc[4][4] = {};
    for (int k0 = 0; k0 < K; k0 += 64) {
#pragma unroll
        for (int p = 0; p < 4; ++p) {
            int r = p * 32 + lrow;
            *(f16x8*)&As[r][lcol] = *(const f16x8*)&A[(arow0 + r) * K + k0 + lcol];
            *(f16x8*)&Bs[r][lcol] = *(const f16x8*)&Wt[(size_t)(bn * 128 + r) * K + k0 + lcol];
        }
        __syncthreads();
#pragma unroll
        for (int ks = 0; ks < 64; ks += 32) {
            f16x8 af[4], bfr[4];
#pragma unroll
            for (int i = 0; i < 4; ++i) af[i]  = *(const f16x8*)&As[wm + i * 16 + mrow][ks + kq];
#pragma unroll
            for (int j = 0; j < 4; ++j) bfr[j] = *(const f16x8*)&Bs[wn + j * 16 + mrow][ks + kq];
#pragma unroll
            for (int i = 0; i < 4; ++i)
#pragma unroll
                for (int j = 0; j < 4; ++j)
                    acc[i][j] = __builtin_amdgcn_mfma_f32_16x16x32_f16(af[i], bfr[j], acc[i][j], 0, 0, 0);
        }
        __syncthreads();
    }
    // C/D layout (verified m89/m91): col = lane&15, row = (lane>>4)*4 + reg
    int col = lane & 15, rb = (lane >> 4) * 4;
#pragma unroll
    for (int j = 0; j < 4; ++j) {
        int n = bn * 128 + wn + j * 16 + col;
        float bo = b_out[n];
#pragma unroll
        for (int i = 0; i < 4; ++i)
#pragma unroll
            for (int r = 0; r < 4; ++r) {
                size_t m = arow0 + wm + i * 16 + rb + r;
                R[m * N + n] = (_Float16)(acc[i][j][r] + bo);
            }
    }
}

// ---------------------------------------------------------------------------
// K4: out[b,d,h,t,s] = sum_f qk[b,d,h,t,f] * R[(b*T+t)*S+s][h*64+f]
// One block per (b,h,t, d-half): M=128(d) x N=128(s) x K=64(f).
// ---------------------------------------------------------------------------
__global__ __launch_bounds__(256) void k_einsum(
    const float* __restrict__ qk, const _Float16* __restrict__ R,
    float* __restrict__ out)
{
    __shared__ _Float16 Aq[128][72];
    __shared__ _Float16 Br[128][72];
    int bht  = blockIdx.x;          // b*H*T + h*T + t
    int dblk = blockIdx.y;          // 0 / 1
    int t = bht & 127;
    int h = (bht >> 7) & 7;
    int b = bht >> 10;
    int tid = threadIdx.x;
    int wave = tid >> 6, lane = tid & 63;
    int wm = (wave >> 1) * 64, wn = (wave & 1) * 64;

    // stage A: qk rows d = dblk*128 .. +127, 64 fp32 each -> f16 LDS
    const size_t qbase = (size_t)b * (D_ * H_ * T_ * F_) + (size_t)h * (T_ * F_)
                       + (size_t)t * F_ + (size_t)dblk * 128 * (H_ * T_ * F_);
    {
        int r  = tid >> 4;          // 16 rows per pass
        int c4 = (tid & 15) * 4;
#pragma unroll
        for (int p = 0; p < 8; ++p) {
            int row = p * 16 + r;
            float4 v = *(const float4*)&qk[qbase + (size_t)row * (H_ * T_ * F_) + c4];
            f16x4 hv;
            hv.x = (_Float16)v.x; hv.y = (_Float16)v.y;
            hv.z = (_Float16)v.z; hv.w = (_Float16)v.w;
            *(f16x4*)&Aq[row][c4] = hv;
        }
    }
    // stage B: R rows (b*T+t)*S + s, col offset h*64
    {
        const size_t rbase = ((size_t)(b * T_ + t) * S_) * C_ + h * 64;
        int r  = tid >> 3;          // 32 rows per pass
        int c8 = (tid & 7) * 8;
#pragma unroll
        for (int p = 0; p < 4; ++p) {
            int row = p * 32 + r;
            *(f16x8*)&Br[row][c8] = *(const f16x8*)&R[rbase + (size_t)row * C_ + c8];
        }
    }
    __syncthreads();

    int mrow = lane & 15, kq = (lane >> 4) * 8;
    f32x4 acc[4][4] = {};
#pragma unroll
    for (int ks = 0; ks < 64; ks += 32) {
        f16x8 af[4], bfr[4];
#pragma unroll
        for (int i = 0; i < 4; ++i) af[i]  = *(const f16x8*)&Aq[wm + i * 16 + mrow][ks + kq];
#pragma unroll
        for (int j = 0; j < 4; ++j) bfr[j] = *(const f16x8*)&Br[wn + j * 16 + mrow][ks + kq];
#pragma unroll
        for (int i = 0; i < 4; ++i)
#pragma unroll
            for (int j = 0; j < 4; ++j)
                acc[i][j] = __builtin_amdgcn_mfma_f32_16x16x32_f16(af[i], bfr[j], acc[i][j], 0, 0, 0);
    }

    const size_t obase = (size_t)b * (D_ * H_ * T_ * S_) + (size_t)h * (T_ * S_)
                       + (size_t)t * S_ + (size_t)dblk * 128 * (H_ * T_ * S_);
    int col = lane & 15, rb = (lane >> 4) * 4;
#pragma unroll
    for (int i = 0; i < 4; ++i)
#pragma unroll
        for (int r = 0; r < 4; ++r) {
            int dloc = wm + i * 16 + rb + r;
            size_t o = obase + (size_t)dloc * (H_ * T_ * S_);
#pragma unroll
            for (int j = 0; j < 4; ++j)
                out[o + wn + j * 16 + col] = acc[i][j][r];
        }
}

// ---------------------------------------------------------------------------
extern "C" void kernel_launch(void* const* d_in, const int* in_sizes, int n_in,
                              void* d_out, int out_size, void* d_ws, size_t ws_size,
                              hipStream_t stream) {
    (void)in_sizes; (void)n_in; (void)out_size; (void)ws_size;
    const float* qk     = (const float*)d_in[0];
    const float* temb   = (const float*)d_in[1];
    const int*   pd     = (const int*)d_in[2];
    const float* w_dist = (const float*)d_in[3];
    const float* b_dist = (const float*)d_in[4];
    const float* w_time = (const float*)d_in[5];
    const float* b_time = (const float*)d_in[6];
    const float* w_out  = (const float*)d_in[7];
    const float* b_out  = (const float*)d_in[8];
    float* out = (float*)d_out;

    char* ws = (char*)d_ws;
    float*     tp = (float*)ws;                                  // 512 KB
    _Float16*  Wt = (_Float16*)(ws + 512 * 1024);                // 512 KB
    _Float16*  A  = (_Float16*)(ws + 1024 * 1024);               // 32 MB
    _Float16*  R  = (_Float16*)(ws + 1024 * 1024 + 33554432);    // 32 MB

    k_time_proj<<<dim3(B_ * T_ / 2), dim3(256), 0, stream>>>(temb, w_time, b_time, b_dist, tp);
    k_wt<<<dim3(C_), dim3(C_), 0, stream>>>(w_out, Wt);
    k_embed_silu<<<dim3(B_ * T_ * S_), dim3(128), 0, stream>>>(tp, pd, w_dist, A);
    k_gemm_R<<<dim3(256, 4), dim3(256), 0, stream>>>(A, Wt, b_out, R);
    k_einsum<<<dim3(B_ * H_ * T_, 2), dim3(256), 0, stream>>>(qk, R, out);
}